// Round 1
// baseline (100.413 us; speedup 1.0000x reference)
//
#include <hip/hip_runtime.h>
#include <math.h>

#define TPB 256      // threads per block
#define IPT 2        // "self" points per thread (registers)
#define TILE 512     // "other" points staged in LDS per block (8 KB as float4)

// ---------------------------------------------------------------------------
// Kernel 1: apply rigid transform to src points; repack both clouds as float4
// (SoA-ish 16B elements so the pairs kernel can ds_read_b128 one point).
// kpts2[j,c] = sum_k src[j,k]*T[c,k] + T[c,3]
// ---------------------------------------------------------------------------
__global__ __launch_bounds__(256) void transform_kernel(
    const float* __restrict__ ref, const float* __restrict__ src,
    const float* __restrict__ T, float4* __restrict__ r4,
    float4* __restrict__ s4, int N, int M) {
  int i = blockIdx.x * blockDim.x + threadIdx.x;
  if (i < M) {
    float x = src[3 * i], y = src[3 * i + 1], z = src[3 * i + 2];
    float tx = T[0] * x + T[1] * y + T[2]  * z + T[3];
    float ty = T[4] * x + T[5] * y + T[6]  * z + T[7];
    float tz = T[8] * x + T[9] * y + T[10] * z + T[11];
    s4[i] = make_float4(tx, ty, tz, 0.f);
  }
  if (i < N) {
    r4[i] = make_float4(ref[3 * i], ref[3 * i + 1], ref[3 * i + 2], 0.f);
  }
}

// ---------------------------------------------------------------------------
// Kernel 2: fused bidirectional pairwise min+argmin over SQUARED distance.
// Block role decoded from blockIdx: forward blocks track per-ref min over a
// src j-slice; backward blocks track per-src min over a ref i-slice.
// Partial (d2,idx) combined across slices via packed-u64 atomicMin:
//   pack = (float_bits(d2) << 32) | j   -- d2 >= 0 so bits are order-preserving,
//   and ties resolve to the smallest index == jnp.argmin semantics.
// ---------------------------------------------------------------------------
__global__ __launch_bounds__(TPB) void pairs_kernel(
    const float4* __restrict__ r4, const float4* __restrict__ s4,
    unsigned long long* __restrict__ packF,
    unsigned long long* __restrict__ packB,
    int N, int M, int nbF, int jsF, int jsB) {
  __shared__ float4 tile[TILE];

  int b = blockIdx.x;
  const float4* selfp;
  const float4* other;
  unsigned long long* pack;
  int selfN, otherN, ib, jb;
  if (b < nbF) {  // forward: self = ref, other = transformed src
    selfp = r4; other = s4; pack = packF; selfN = N; otherN = M;
    ib = b / jsF; jb = b % jsF;
  } else {        // backward: self = transformed src, other = ref
    b -= nbF;
    selfp = s4; other = r4; pack = packB; selfN = M; otherN = N;
    ib = b / jsB; jb = b % jsB;
  }

  const int i0 = ib * (TPB * IPT) + threadIdx.x;

  float px[IPT], py[IPT], pz[IPT], mind[IPT];
  int mini[IPT];
#pragma unroll
  for (int k = 0; k < IPT; k++) {
    int i = i0 + k * TPB;
    float4 p = (i < selfN) ? selfp[i] : make_float4(0.f, 0.f, 0.f, 0.f);
    px[k] = p.x; py[k] = p.y; pz[k] = p.z;
    mind[k] = INFINITY; mini[k] = 0;
  }

  const int j0 = jb * TILE;
  const int jcount = min(TILE, otherN - j0);
  for (int t = threadIdx.x; t < jcount; t += TPB) tile[t] = other[j0 + t];
  __syncthreads();

#pragma unroll 4
  for (int jj = 0; jj < jcount; jj++) {
    float4 q = tile[jj];  // wave-uniform address -> LDS broadcast, no conflict
#pragma unroll
    for (int k = 0; k < IPT; k++) {
      float dx = px[k] - q.x;
      float dy = py[k] - q.y;
      float dz = pz[k] - q.z;
      float d2 = fmaf(dx, dx, fmaf(dy, dy, dz * dz));
      bool lt = d2 < mind[k];   // strict < keeps earliest j on ties
      mind[k] = lt ? d2 : mind[k];
      mini[k] = lt ? jj : mini[k];
    }
  }

#pragma unroll
  for (int k = 0; k < IPT; k++) {
    int i = i0 + k * TPB;
    if (i < selfN) {
      unsigned long long p =
          ((unsigned long long)__float_as_uint(mind[k]) << 32) |
          (unsigned int)(j0 + mini[k]);
      atomicMin(&pack[i], p);
    }
  }
}

// ---------------------------------------------------------------------------
// Kernel 3: epilogue. Unpack winners, sqrt once, sigma gather, log, mean both
// directions, one atomicAdd per block into d_out (pre-zeroed).
// ---------------------------------------------------------------------------
__global__ __launch_bounds__(256) void finalize_kernel(
    const unsigned long long* __restrict__ packF,
    const unsigned long long* __restrict__ packB,
    const float* __restrict__ ref_sigma, const float* __restrict__ src_sigma,
    float* __restrict__ out, int N, int M) {
  int gid = blockIdx.x * blockDim.x + threadIdx.x;
  float term = 0.f;
  if (gid < N) {
    unsigned long long p = packF[gid];
    float d = sqrtf(__uint_as_float((unsigned int)(p >> 32)));
    int idx = (int)(p & 0xffffffffu);
    float sigma = 0.5f * (ref_sigma[gid] + src_sigma[idx]);
    term = (logf(sigma) + d / sigma) * (1.0f / (float)N);
  } else if (gid < N + M) {
    int j = gid - N;
    unsigned long long p = packB[j];
    float d = sqrtf(__uint_as_float((unsigned int)(p >> 32)));
    int idx = (int)(p & 0xffffffffu);
    float sigma = 0.5f * (src_sigma[j] + ref_sigma[idx]);
    term = (logf(sigma) + d / sigma) * (1.0f / (float)M);
  }
  // wave reduce (64-wide) then cross-wave via LDS
#pragma unroll
  for (int off = 32; off > 0; off >>= 1) term += __shfl_down(term, off, 64);
  __shared__ float wsum[4];
  int lane = threadIdx.x & 63, wid = threadIdx.x >> 6;
  if (lane == 0) wsum[wid] = term;
  __syncthreads();
  if (threadIdx.x == 0) {
    float s = wsum[0] + wsum[1] + wsum[2] + wsum[3];
    atomicAdd(out, s);
  }
}

extern "C" void kernel_launch(void* const* d_in, const int* in_sizes, int n_in,
                              void* d_out, int out_size, void* d_ws,
                              size_t ws_size, hipStream_t stream) {
  const float* ref_kpts  = (const float*)d_in[0];
  const float* src_kpts  = (const float*)d_in[1];
  const float* gt        = (const float*)d_in[2];
  const float* ref_sigma = (const float*)d_in[3];
  const float* src_sigma = (const float*)d_in[4];
  float* out = (float*)d_out;

  const int N = in_sizes[0] / 3;
  const int M = in_sizes[1] / 3;

  // workspace layout
  char* ws = (char*)d_ws;
  float4* r4 = (float4*)ws;                       // N * 16 B
  float4* s4 = (float4*)(ws + (size_t)N * 16);    // M * 16 B
  unsigned long long* packF =
      (unsigned long long*)(ws + (size_t)(N + M) * 16);          // N * 8 B
  unsigned long long* packB = packF + N;                          // M * 8 B

  // init: pack arrays to u64-max (0xFF bytes), output accumulator to zero
  hipMemsetAsync(packF, 0xFF, (size_t)(N + M) * 8, stream);
  hipMemsetAsync(out, 0, sizeof(float), stream);

  int nPts = (N > M) ? N : M;
  transform_kernel<<<(nPts + 255) / 256, 256, 0, stream>>>(
      ref_kpts, src_kpts, gt, r4, s4, N, M);

  const int jsF = (M + TILE - 1) / TILE;               // j-slices (forward)
  const int jsB = (N + TILE - 1) / TILE;               // i-slices (backward)
  const int ibF = (N + TPB * IPT - 1) / (TPB * IPT);   // row-blocks (forward)
  const int ibB = (M + TPB * IPT - 1) / (TPB * IPT);   // row-blocks (backward)
  const int nbF = ibF * jsF;
  const int nbB = ibB * jsB;
  pairs_kernel<<<nbF + nbB, TPB, 0, stream>>>(r4, s4, packF, packB, N, M, nbF,
                                              jsF, jsB);

  finalize_kernel<<<(N + M + 255) / 256, 256, 0, stream>>>(
      packF, packB, ref_sigma, src_sigma, out, N, M);
}

// Round 2
// 95.043 us; speedup vs baseline: 1.0565x; 1.0565x over previous
//
#include <hip/hip_runtime.h>
#include <math.h>

#define TPB 256   // threads per block
#define IPT 4     // "self" rows per thread (registers)
#define JS  32    // j-slices per direction (split-K over the other cloud)

// ---------------------------------------------------------------------------
// Kernel 1: transform src by the rigid transform; repack both clouds as
// float4 (x, y, z, |v|^2). The .w squared-norm feeds the dot-product-trick
// score in the pairs kernel.
// ---------------------------------------------------------------------------
__global__ __launch_bounds__(256) void transform_kernel(
    const float* __restrict__ ref, const float* __restrict__ src,
    const float* __restrict__ T, float4* __restrict__ r4,
    float4* __restrict__ s4, int N, int M) {
  int i = blockIdx.x * blockDim.x + threadIdx.x;
  if (i < M) {
    float x = src[3 * i], y = src[3 * i + 1], z = src[3 * i + 2];
    float tx = T[0] * x + T[1] * y + T[2]  * z + T[3];
    float ty = T[4] * x + T[5] * y + T[6]  * z + T[7];
    float tz = T[8] * x + T[9] * y + T[10] * z + T[11];
    s4[i] = make_float4(tx, ty, tz, tx * tx + ty * ty + tz * tz);
  }
  if (i < N) {
    float x = ref[3 * i], y = ref[3 * i + 1], z = ref[3 * i + 2];
    r4[i] = make_float4(x, y, z, x * x + y * y + z * z);
  }
}

// ---------------------------------------------------------------------------
// Kernel 2: fused bidirectional argmin over score_j = |q_j|^2 - 2 p.q_j
// (equal-argmin to squared distance; |p|^2 is row-constant).
//   - q is wave-uniform -> compiler scalarizes to s_load_dwordx4 (no LDS!)
//   - per pair: 3 v_fma + v_cmp + 2 v_cndmask = 6 VALU
//   - split-K partials merged via sortable-key packed-u64 atomicMin:
//       key = float_bits(score) sign-flipped to unsigned order, low32 = j.
//     Tie-break lands on the smallest j == jnp.argmin first-occurrence.
// Exact distance is recomputed from the winning index in the epilogue, so
// score roundoff only risks argmin flips on ~1e-6 ties.
// ---------------------------------------------------------------------------
__global__ __launch_bounds__(TPB) void pairs_kernel(
    const float4* __restrict__ r4, const float4* __restrict__ s4,
    unsigned long long* __restrict__ packF,
    unsigned long long* __restrict__ packB,
    int N, int M, int nbF) {
  int b = blockIdx.x;
  const float4* selfp;
  const float4* other;
  unsigned long long* pack;
  int selfN, otherN, ib, jb;
  if (b < nbF) {  // forward: self = ref, other = transformed src
    selfp = r4; other = s4; pack = packF; selfN = N; otherN = M;
    ib = b / JS; jb = b % JS;
  } else {        // backward: self = transformed src, other = ref
    b -= nbF;
    selfp = s4; other = r4; pack = packB; selfN = M; otherN = N;
    ib = b / JS; jb = b % JS;
  }

  const int i0 = ib * (TPB * IPT) + threadIdx.x;

  float px[IPT], py[IPT], pz[IPT], mind[IPT];
  int mini[IPT];
#pragma unroll
  for (int k = 0; k < IPT; k++) {
    int i = i0 + k * TPB;
    int ic = (i < selfN) ? i : (selfN - 1);  // clamp: guarded at atomic time
    float4 p = selfp[ic];
    px[k] = -2.0f * p.x; py[k] = -2.0f * p.y; pz[k] = -2.0f * p.z;
    mind[k] = INFINITY; mini[k] = 0;
  }

  const int chunk = (otherN + JS - 1) / JS;
  const int j0 = jb * chunk;
  const int jcount = min(chunk, otherN - j0);

#pragma unroll 4
  for (int jj = 0; jj < jcount; jj++) {
    float4 q = other[j0 + jj];  // wave-uniform -> s_load_dwordx4, scalar pipe
#pragma unroll
    for (int k = 0; k < IPT; k++) {
      float t = fmaf(px[k], q.x, q.w);
      t = fmaf(py[k], q.y, t);
      t = fmaf(pz[k], q.z, t);
      bool lt = t < mind[k];   // strict < keeps earliest j on ties
      mind[k] = lt ? t : mind[k];
      mini[k] = lt ? jj : mini[k];
    }
  }

#pragma unroll
  for (int k = 0; k < IPT; k++) {
    int i = i0 + k * TPB;
    if (i < selfN) {
      unsigned int u = __float_as_uint(mind[k]);
      u ^= (unsigned int)((int)u >> 31) | 0x80000000u;  // sortable key
      unsigned long long p = ((unsigned long long)u << 32) |
                             (unsigned int)(j0 + mini[k]);
      atomicMin(&pack[i], p);
    }
  }
}

// ---------------------------------------------------------------------------
// Kernel 3: epilogue. Gather winning index, recompute EXACT fp32 distance,
// sigma gather, log, mean both directions, one atomicAdd per block.
// ---------------------------------------------------------------------------
__global__ __launch_bounds__(256) void finalize_kernel(
    const unsigned long long* __restrict__ packF,
    const unsigned long long* __restrict__ packB,
    const float4* __restrict__ r4, const float4* __restrict__ s4,
    const float* __restrict__ ref_sigma, const float* __restrict__ src_sigma,
    float* __restrict__ out, int N, int M) {
  int gid = blockIdx.x * blockDim.x + threadIdx.x;
  float term = 0.f;
  if (gid < N) {
    int idx = (int)(packF[gid] & 0xffffffffu);
    float4 p = r4[gid];
    float4 q = s4[idx];
    float dx = p.x - q.x, dy = p.y - q.y, dz = p.z - q.z;
    float d = sqrtf(dx * dx + dy * dy + dz * dz);
    float sigma = 0.5f * (ref_sigma[gid] + src_sigma[idx]);
    term = (logf(sigma) + d / sigma) * (1.0f / (float)N);
  } else if (gid < N + M) {
    int j = gid - N;
    int idx = (int)(packB[j] & 0xffffffffu);
    float4 p = s4[j];
    float4 q = r4[idx];
    float dx = p.x - q.x, dy = p.y - q.y, dz = p.z - q.z;
    float d = sqrtf(dx * dx + dy * dy + dz * dz);
    float sigma = 0.5f * (src_sigma[j] + ref_sigma[idx]);
    term = (logf(sigma) + d / sigma) * (1.0f / (float)M);
  }
  // wave reduce (64-wide) then cross-wave via LDS
#pragma unroll
  for (int off = 32; off > 0; off >>= 1) term += __shfl_down(term, off, 64);
  __shared__ float wsum[4];
  int lane = threadIdx.x & 63, wid = threadIdx.x >> 6;
  if (lane == 0) wsum[wid] = term;
  __syncthreads();
  if (threadIdx.x == 0) {
    float s = wsum[0] + wsum[1] + wsum[2] + wsum[3];
    atomicAdd(out, s);
  }
}

extern "C" void kernel_launch(void* const* d_in, const int* in_sizes, int n_in,
                              void* d_out, int out_size, void* d_ws,
                              size_t ws_size, hipStream_t stream) {
  const float* ref_kpts  = (const float*)d_in[0];
  const float* src_kpts  = (const float*)d_in[1];
  const float* gt        = (const float*)d_in[2];
  const float* ref_sigma = (const float*)d_in[3];
  const float* src_sigma = (const float*)d_in[4];
  float* out = (float*)d_out;

  const int N = in_sizes[0] / 3;
  const int M = in_sizes[1] / 3;

  // workspace layout
  char* ws = (char*)d_ws;
  float4* r4 = (float4*)ws;                       // N * 16 B
  float4* s4 = (float4*)(ws + (size_t)N * 16);    // M * 16 B
  unsigned long long* packF =
      (unsigned long long*)(ws + (size_t)(N + M) * 16);  // N * 8 B
  unsigned long long* packB = packF + N;                  // M * 8 B

  // init: pack arrays to u64-max (0xFF bytes), output accumulator to zero
  hipMemsetAsync(packF, 0xFF, (size_t)(N + M) * 8, stream);
  hipMemsetAsync(out, 0, sizeof(float), stream);

  int nPts = (N > M) ? N : M;
  transform_kernel<<<(nPts + 255) / 256, 256, 0, stream>>>(
      ref_kpts, src_kpts, gt, r4, s4, N, M);

  const int ibF = (N + TPB * IPT - 1) / (TPB * IPT);  // row-blocks (forward)
  const int ibB = (M + TPB * IPT - 1) / (TPB * IPT);  // row-blocks (backward)
  const int nbF = ibF * JS;
  const int nbB = ibB * JS;
  pairs_kernel<<<nbF + nbB, TPB, 0, stream>>>(r4, s4, packF, packB, N, M, nbF);

  finalize_kernel<<<(N + M + 255) / 256, 256, 0, stream>>>(
      packF, packB, r4, s4, ref_sigma, src_sigma, out, N, M);
}

// Round 3
// 93.896 us; speedup vs baseline: 1.0694x; 1.0122x over previous
//
#include <hip/hip_runtime.h>
#include <math.h>

typedef float v2f __attribute__((ext_vector_type(2)));

#define TPB 256   // threads per block
#define IPT 4     // "self" rows per thread (registers)
#define JS  32    // j-slices per direction (split-K over the other cloud)

// ---------------------------------------------------------------------------
// Kernel 1 (fused setup): transform src, repack BOTH clouds as SoA
// (x[], y[], z[], w[]=|v|^2), init pack arrays to u64-max, zero the output
// accumulator, and write +INF sentinel pads so the 2-wide j-loop tail can
// safely read one element past the end.
// ---------------------------------------------------------------------------
__global__ __launch_bounds__(256) void setup_kernel(
    const float* __restrict__ ref, const float* __restrict__ src,
    const float* __restrict__ T,
    float* __restrict__ rx, float* __restrict__ ry, float* __restrict__ rz,
    float* __restrict__ rw,
    float* __restrict__ sx, float* __restrict__ sy, float* __restrict__ sz,
    float* __restrict__ sw,
    unsigned long long* __restrict__ packF,
    unsigned long long* __restrict__ packB,
    float* __restrict__ out, int N, int M) {
  int i = blockIdx.x * blockDim.x + threadIdx.x;
  if (i < M) {
    float x = src[3 * i], y = src[3 * i + 1], z = src[3 * i + 2];
    float tx = T[0] * x + T[1] * y + T[2]  * z + T[3];
    float ty = T[4] * x + T[5] * y + T[6]  * z + T[7];
    float tz = T[8] * x + T[9] * y + T[10] * z + T[11];
    sx[i] = tx; sy[i] = ty; sz[i] = tz;
    sw[i] = tx * tx + ty * ty + tz * tz;
    packB[i] = ~0ull;
  }
  if (i < N) {
    float x = ref[3 * i], y = ref[3 * i + 1], z = ref[3 * i + 2];
    rx[i] = x; ry[i] = y; rz[i] = z;
    rw[i] = x * x + y * y + z * z;
    packF[i] = ~0ull;
  }
  if (i == 0) {
    out[0] = 0.0f;
    rx[N] = 0.f; ry[N] = 0.f; rz[N] = 0.f; rw[N] = INFINITY;  // pad sentinel
    sx[M] = 0.f; sy[M] = 0.f; sz[M] = 0.f; sw[M] = INFINITY;  // pad sentinel
  }
}

// ---------------------------------------------------------------------------
// Kernel 2: fused bidirectional argmin over score_j = |q_j|^2 - 2 p.q_j
// (equal-argmin to squared distance; |p|^2 is row-constant).
//   - two j's per step via float2 ext-vectors -> v_pk_fma_f32: 3 pk-fma
//     produce 2 scores; row splats (-2*p) are loop-invariant so no repack.
//   - per pair: 1.5 pk-fma + cmp + 2 cndmask = 4.5 VALU
//   - sequential strict-< selects (x half then y half) preserve the
//     first-occurrence (smallest j) tie-break == jnp.argmin.
//   - split-K partials merged via sortable-key packed-u64 atomicMin.
//   - odd tails: the pair-load may read one past the chunk; interior chunks
//     then score a neighbor chunk's j (valid, idempotent under min), the
//     global end reads the +INF pad (never wins).
// Exact distance is recomputed from the winning index in the epilogue.
// ---------------------------------------------------------------------------
__global__ __launch_bounds__(TPB) void pairs_kernel(
    const float* __restrict__ rx, const float* __restrict__ ry,
    const float* __restrict__ rz, const float* __restrict__ rw,
    const float* __restrict__ sx, const float* __restrict__ sy,
    const float* __restrict__ sz, const float* __restrict__ sw,
    unsigned long long* __restrict__ packF,
    unsigned long long* __restrict__ packB,
    int N, int M, int nbF) {
  int b = blockIdx.x;
  const float *px_, *py_, *pz_, *ox, *oy, *oz, *ow;
  unsigned long long* pack;
  int selfN, otherN;
  if (b < nbF) {  // forward: self = ref, other = transformed src
    px_ = rx; py_ = ry; pz_ = rz;
    ox = sx; oy = sy; oz = sz; ow = sw;
    pack = packF; selfN = N; otherN = M;
  } else {        // backward: self = transformed src, other = ref
    b -= nbF;
    px_ = sx; py_ = sy; pz_ = sz;
    ox = rx; oy = ry; oz = rz; ow = rw;
    pack = packB; selfN = M; otherN = N;
  }
  const int ib = b / JS, jb = b % JS;
  const int i0 = ib * (TPB * IPT) + threadIdx.x;

  v2f pxv[IPT], pyv[IPT], pzv[IPT];
  float mind[IPT];
  int mini[IPT];
#pragma unroll
  for (int k = 0; k < IPT; k++) {
    int i = i0 + k * TPB;
    int ic = (i < selfN) ? i : (selfN - 1);  // clamp; guarded at atomic time
    float ax = -2.0f * px_[ic], ay = -2.0f * py_[ic], az = -2.0f * pz_[ic];
    pxv[k] = (v2f){ax, ax}; pyv[k] = (v2f){ay, ay}; pzv[k] = (v2f){az, az};
    mind[k] = INFINITY; mini[k] = 0;
  }

  int chunk = (otherN + JS - 1) / JS;
  chunk = (chunk + 1) & ~1;  // even, so j0 stays 8B-aligned for v2f loads
  const int j0 = jb * chunk;
  const int jcount = min(chunk, otherN - j0);  // may be <= 0

#pragma unroll 2
  for (int jj = 0; jj < jcount; jj += 2) {
    v2f qx = *(const v2f*)(ox + j0 + jj);  // wave-uniform broadcast loads
    v2f qy = *(const v2f*)(oy + j0 + jj);
    v2f qz = *(const v2f*)(oz + j0 + jj);
    v2f qw = *(const v2f*)(ow + j0 + jj);
#pragma unroll
    for (int k = 0; k < IPT; k++) {
      v2f t = __builtin_elementwise_fma(pxv[k], qx, qw);
      t = __builtin_elementwise_fma(pyv[k], qy, t);
      t = __builtin_elementwise_fma(pzv[k], qz, t);
      if (t.x < mind[k]) { mind[k] = t.x; mini[k] = jj; }
      if (t.y < mind[k]) { mind[k] = t.y; mini[k] = jj + 1; }
    }
  }

#pragma unroll
  for (int k = 0; k < IPT; k++) {
    int i = i0 + k * TPB;
    if (i < selfN) {
      unsigned int u = __float_as_uint(mind[k]);
      u ^= (unsigned int)((int)u >> 31) | 0x80000000u;  // sortable key
      unsigned long long p = ((unsigned long long)u << 32) |
                             (unsigned int)(j0 + mini[k]);
      atomicMin(&pack[i], p);
    }
  }
}

// ---------------------------------------------------------------------------
// Kernel 3: epilogue. Gather winning index, recompute EXACT fp32 distance,
// sigma gather, log, mean both directions, one atomicAdd per block.
// ---------------------------------------------------------------------------
__global__ __launch_bounds__(256) void finalize_kernel(
    const unsigned long long* __restrict__ packF,
    const unsigned long long* __restrict__ packB,
    const float* __restrict__ rx, const float* __restrict__ ry,
    const float* __restrict__ rz,
    const float* __restrict__ sx, const float* __restrict__ sy,
    const float* __restrict__ sz,
    const float* __restrict__ ref_sigma, const float* __restrict__ src_sigma,
    float* __restrict__ out, int N, int M) {
  int gid = blockIdx.x * blockDim.x + threadIdx.x;
  float term = 0.f;
  if (gid < N) {
    int idx = (int)(packF[gid] & 0xffffffffu);
    float dx = rx[gid] - sx[idx], dy = ry[gid] - sy[idx],
          dz = rz[gid] - sz[idx];
    float d = sqrtf(dx * dx + dy * dy + dz * dz);
    float sigma = 0.5f * (ref_sigma[gid] + src_sigma[idx]);
    term = (logf(sigma) + d / sigma) * (1.0f / (float)N);
  } else if (gid < N + M) {
    int j = gid - N;
    int idx = (int)(packB[j] & 0xffffffffu);
    float dx = sx[j] - rx[idx], dy = sy[j] - ry[idx], dz = sz[j] - rz[idx];
    float d = sqrtf(dx * dx + dy * dy + dz * dz);
    float sigma = 0.5f * (src_sigma[j] + ref_sigma[idx]);
    term = (logf(sigma) + d / sigma) * (1.0f / (float)M);
  }
  // wave reduce (64-wide) then cross-wave via LDS
#pragma unroll
  for (int off = 32; off > 0; off >>= 1) term += __shfl_down(term, off, 64);
  __shared__ float wsum[4];
  int lane = threadIdx.x & 63, wid = threadIdx.x >> 6;
  if (lane == 0) wsum[wid] = term;
  __syncthreads();
  if (threadIdx.x == 0) {
    float s = wsum[0] + wsum[1] + wsum[2] + wsum[3];
    atomicAdd(out, s);
  }
}

extern "C" void kernel_launch(void* const* d_in, const int* in_sizes, int n_in,
                              void* d_out, int out_size, void* d_ws,
                              size_t ws_size, hipStream_t stream) {
  const float* ref_kpts  = (const float*)d_in[0];
  const float* src_kpts  = (const float*)d_in[1];
  const float* gt        = (const float*)d_in[2];
  const float* ref_sigma = (const float*)d_in[3];
  const float* src_sigma = (const float*)d_in[4];
  float* out = (float*)d_out;

  const int N = in_sizes[0] / 3;
  const int M = in_sizes[1] / 3;

  // workspace layout (SoA, each array padded +1 sentinel, stride rounded to
  // 4 floats so every array base stays 16B-aligned)
  const int NP = (N + 1 + 3) & ~3;
  const int MP = (M + 1 + 3) & ~3;
  float* f = (float*)d_ws;
  float* rx = f;            float* ry = f + NP;
  float* rz = f + 2 * NP;   float* rw = f + 3 * NP;
  float* sx = f + 4 * NP;           float* sy = f + 4 * NP + MP;
  float* sz = f + 4 * NP + 2 * MP;  float* sw = f + 4 * NP + 3 * MP;
  unsigned long long* packF = (unsigned long long*)(f + 4 * NP + 4 * MP);
  unsigned long long* packB = packF + N;

  int nPts = (N > M) ? N : M;
  setup_kernel<<<(nPts + 255) / 256, 256, 0, stream>>>(
      ref_kpts, src_kpts, gt, rx, ry, rz, rw, sx, sy, sz, sw, packF, packB,
      out, N, M);

  const int ibF = (N + TPB * IPT - 1) / (TPB * IPT);  // row-blocks (forward)
  const int ibB = (M + TPB * IPT - 1) / (TPB * IPT);  // row-blocks (backward)
  const int nbF = ibF * JS;
  const int nbB = ibB * JS;
  pairs_kernel<<<nbF + nbB, TPB, 0, stream>>>(rx, ry, rz, rw, sx, sy, sz, sw,
                                              packF, packB, N, M, nbF);

  finalize_kernel<<<(N + M + 255) / 256, 256, 0, stream>>>(
      packF, packB, rx, ry, rz, sx, sy, sz, ref_sigma, src_sigma, out, N, M);
}